// Round 7
// baseline (3884.684 us; speedup 1.0000x reference)
//
#include <hip/hip_runtime.h>
#include <stdint.h>
#include <math.h>

// Autoregressive LSTM controller. B=4096, EMB=128, HID=512, OUT=64, STEPS=20.
// Round 7: PERSISTENT kernel — all 20 steps in one launch (grid 256 = 1/CU),
// DIY device-scope grid barrier (2/step). c held in registers across steps
// (kills 16MB/step HBM round-trip). GEMM pipeline = R6's 8-phase counted
// vmcnt(8) + 8B-granule zero-conflict LDS swizzle. Fast __expf sigmoid/tanh
// in LSTM epilogue (sampling path unchanged, libm logf).

#define B_SZ  4096
#define EMB   128
#define HID   512
#define NOUT  64
#define STEPS 20
#define G4    2048
#define HF    ((size_t)B_SZ * HID)   // elems per hi/lo plane of h
#define NBLK  256

typedef __attribute__((ext_vector_type(8)))  short bf16x8;
typedef __attribute__((ext_vector_type(16))) float f32x16;

union B8 { uint2 q[2]; bf16x8 v; };

// ---------------- threefry2x32 (JAX partitionable semantics) ----------------
__device__ __forceinline__ void tf2x32(uint32_t k0, uint32_t k1,
                                       uint32_t x0, uint32_t x1,
                                       uint32_t& o0, uint32_t& o1) {
  const uint32_t ks2 = k0 ^ k1 ^ 0x1BD11BDAu;
#define TFR(r) { x0 += x1; x1 = (x1 << (r)) | (x1 >> (32 - (r))); x1 ^= x0; }
  x0 += k0; x1 += k1;
  TFR(13) TFR(15) TFR(26) TFR(6)
  x0 += k1;  x1 += ks2 + 1u;
  TFR(17) TFR(29) TFR(16) TFR(24)
  x0 += ks2; x1 += k0 + 2u;
  TFR(13) TFR(15) TFR(26) TFR(6)
  x0 += k0;  x1 += k1 + 3u;
  TFR(17) TFR(29) TFR(16) TFR(24)
  x0 += k1;  x1 += ks2 + 4u;
  TFR(13) TFR(15) TFR(26) TFR(6)
  x0 += ks2; x1 += k0 + 5u;
#undef TFR
  o0 = x0; o1 = x1;
}

// RNE split of fp32 into bf16 hi + bf16 lo
__device__ __forceinline__ void bf16split(float f, ushort& hi, ushort& lo) {
  uint32_t u = __float_as_uint(f);
  uint32_t r = u + 0x7fffu + ((u >> 16) & 1u);
  hi = (ushort)(r >> 16);
  float fh = __uint_as_float((r >> 16) << 16);
  float fl = f - fh;
  uint32_t v = __float_as_uint(fl);
  uint32_t r2 = v + 0x7fffu + ((v >> 16) & 1u);
  lo = (ushort)(r2 >> 16);
}

__device__ __forceinline__ void gload_lds16(const ushort* g, ushort* d) {
  __builtin_amdgcn_global_load_lds(
      (const __attribute__((address_space(1))) void*)g,
      (__attribute__((address_space(3))) void*)d, 16, 0, 0);
}

// fast sigmoid / tanh via v_exp + v_rcp (err ~1e-7, << 2^-18 split error)
__device__ __forceinline__ float fsig(float x) {
  return __builtin_amdgcn_rcpf(1.f + __expf(-x));
}
__device__ __forceinline__ float ftanh(float x) {
  return 1.f - 2.f * __builtin_amdgcn_rcpf(1.f + __expf(2.f * x));
}

// ---------------- device-scope grid barrier (sense via generation) ----------
__device__ __forceinline__ void gridbar(unsigned* cnt, unsigned* gen) {
  __syncthreads();
  if (threadIdx.x == 0) {
    __threadfence();   // release: drain + L2 writeback (agent scope)
    unsigned g = __hip_atomic_load(gen, __ATOMIC_RELAXED, __HIP_MEMORY_SCOPE_AGENT);
    unsigned a = __hip_atomic_fetch_add(cnt, 1u, __ATOMIC_ACQ_REL, __HIP_MEMORY_SCOPE_AGENT);
    if (a == NBLK - 1) {
      __hip_atomic_store(cnt, 0u, __ATOMIC_RELAXED, __HIP_MEMORY_SCOPE_AGENT);
      __hip_atomic_fetch_add(gen, 1u, __ATOMIC_RELEASE, __HIP_MEMORY_SCOPE_AGENT);
    } else {
      while (__hip_atomic_load(gen, __ATOMIC_ACQUIRE, __HIP_MEMORY_SCOPE_AGENT) == g)
        __builtin_amdgcn_s_sleep(2);
    }
  }
  __syncthreads();
  __threadfence();     // acquire: invalidate stale L1/L2 before reading peers' data
}

// ---------------- E_proj = emb @ W_ih.T + b_ih + b_hh (fp32, once) ----------
__global__ __launch_bounds__(256) void eproj_kernel(
    const float* __restrict__ emb, const float* __restrict__ W_ih,
    const float* __restrict__ b_ih, const float* __restrict__ b_hh,
    float* __restrict__ E) {
  const int t = blockIdx.x;
  __shared__ float es[EMB];
  for (int k = threadIdx.x; k < EMB; k += blockDim.x) es[k] = emb[t * EMB + k];
  __syncthreads();
  for (int j = threadIdx.x; j < G4; j += blockDim.x) {
    const float* w = W_ih + (size_t)j * EMB;
    float acc = 0.f;
#pragma unroll 8
    for (int k = 0; k < EMB; k += 4) {
      float4 wv = *(const float4*)(w + k);
      acc += wv.x * es[k] + wv.y * es[k + 1] + wv.z * es[k + 2] + wv.w * es[k + 3];
    }
    E[(size_t)t * G4 + j] = acc + b_ih[j] + b_hh[j];
  }
}

// ---------------- W_hh -> pre-swizzled staging mirror (once) ----------------
// [ub(16)][kt(8)][plane(2)][row(128)][e(64)], 4-elem (8B) granule swizzle:
// position e holds W[grow][kt*64 + (e ^ ((row&15)<<2))].
__global__ __launch_bounds__(256) void wprep_whh(
    const float* __restrict__ W_hh, ushort* __restrict__ wswz) {
  const int id = blockIdx.x * 256 + threadIdx.x;
  const int ub    = id >> 14;
  const int w14   = id & 16383;
  const int kt    = w14 >> 11;
  const int plane = (w14 >> 10) & 1;
  const int row   = (w14 >> 3) & 127;
  const int ec    = w14 & 7;
  const int grow = (row >> 5) * HID + ub * 32 + (row & 31);
  const int swz = (row & 15) << 2;
  ushort vals[8];
#pragma unroll
  for (int j = 0; j < 8; ++j) {
    const int e = ec * 8 + j;
    const int k = kt * 64 + (e ^ swz);
    ushort hi, lo;
    bf16split(W_hh[(size_t)grow * HID + k], hi, lo);
    vals[j] = plane ? lo : hi;
  }
  *(uint4*)(wswz + (size_t)id * 8) = *(const uint4*)vals;
}

// ---------------- W_lin -> coalesced transpose [k4][o][4] (once) ------------
__global__ __launch_bounds__(256) void wprep_lin(
    const float* __restrict__ W_lin, float* __restrict__ wlt) {
  const int id = blockIdx.x * 256 + threadIdx.x;
  const int j = id & 3, o = (id >> 2) & 63, k4 = id >> 8;
  wlt[id] = W_lin[(size_t)o * HID + k4 * 4 + j];
}

// ---------------- persistent controller: all 20 steps ----------------
__global__ __launch_bounds__(512, 2) void ctrl_persist(
    const int*    __restrict__ x,
    const ushort* __restrict__ wswz,
    const float*  __restrict__ E,
    const float*  __restrict__ wlt,
    const float*  __restrict__ b_lin,
    float*        __restrict__ h_out,
    ushort*       __restrict__ hf0,
    ushort*       __restrict__ hf1,
    int*          __restrict__ tok,
    float*        __restrict__ out,
    unsigned*     __restrict__ bar)
{
  __shared__ ushort Bt[2][16384];      // 2 x 32 KB double buffer
  const int tid = threadIdx.x;
  const int w = tid >> 6, l = tid & 63;
  const int l31 = l & 31, lh = l >> 5;

  const int raw = blockIdx.x;
  const int xq = raw & 7, jq = raw >> 3;     // xq = XCD
  const int ub  = (xq & 3) * 4 + (jq & 3);
  const int mbi = (xq >> 2) * 8 + (jq >> 2);
  const int m0 = mbi * 256 + w * 32;
  const int u0 = ub * 32;
  const int u  = u0 + l31;

  const ushort* wsrc = wswz + (size_t)ub * 131072 + (size_t)(w * 512 + l * 8);
  const int lb0 = raw * 16 + w * 2;          // logits rows for this wave

  f32x16 creg = {};                          // c resident in registers

  for (int t = 0; t < STEPS; ++t) {
    const ushort* hin  = (t & 1) ? hf1 : hf0;
    ushort*       hout = (t & 1) ? hf0 : hf1;
    const int*    tk   = t ? tok : x;

    f32x16 acc[4] = {};

    if (t > 0) {
      const size_t abase = ((size_t)(m0 >> 5) * 64 + lh) * 256 + (size_t)l31 * 8;
      const ushort* a0 = hin + abase;
      const ushort* a1 = hin + HF + abase;
      bf16x8 Aa0[4], Aa1[4], Ab0[4], Ab1[4];

#define SB0 __builtin_amdgcn_sched_barrier(0)
#define STAGE(KT, BUF) { \
  _Pragma("unroll") \
  for (int rr = 0; rr < 4; ++rr) \
    gload_lds16(wsrc + (size_t)(KT) * 16384 + rr * 4096, &Bt[BUF][w * 512 + rr * 4096]); }
#define LOADA(KT, A0v, A1v) { \
  _Pragma("unroll") \
  for (int kc = 0; kc < 4; ++kc) { \
    const size_t ko = (size_t)((KT) * 8 + kc * 2) * 256; \
    A0v[kc] = *(const bf16x8*)(a0 + ko); \
    A1v[kc] = *(const bf16x8*)(a1 + ko); } }
#define COMPUTE(BUF, A0v, A1v) { \
  __builtin_amdgcn_s_setprio(1); \
  _Pragma("unroll") \
  for (int kc = 0; kc < 4; ++kc) { \
    _Pragma("unroll") \
    for (int s = 0; s < 4; ++s) { \
      const int row = s * 32 + l31; \
      const int swz = (row & 15) << 2; \
      const int eb = kc * 16 + lh * 8; \
      const ushort* rb = &Bt[BUF][row * 64]; \
      B8 uh, ul; \
      uh.q[0] = *(const uint2*)(rb + ((eb)     ^ swz)); \
      uh.q[1] = *(const uint2*)(rb + ((eb + 4) ^ swz)); \
      ul.q[0] = *(const uint2*)(rb + 8192 + ((eb)     ^ swz)); \
      ul.q[1] = *(const uint2*)(rb + 8192 + ((eb + 4) ^ swz)); \
      acc[s] = __builtin_amdgcn_mfma_f32_32x32x16_bf16(A0v[kc], uh.v, acc[s], 0, 0, 0); \
      acc[s] = __builtin_amdgcn_mfma_f32_32x32x16_bf16(A1v[kc], uh.v, acc[s], 0, 0, 0); \
      acc[s] = __builtin_amdgcn_mfma_f32_32x32x16_bf16(A0v[kc], ul.v, acc[s], 0, 0, 0); } } \
  __builtin_amdgcn_s_setprio(0); }
#define FENCE8 { asm volatile("s_waitcnt vmcnt(8)" ::: "memory"); SB0; \
                 __builtin_amdgcn_s_barrier(); }

      STAGE(0, 0); SB0; LOADA(0, Aa0, Aa1); SB0;
      FENCE8;
      STAGE(1, 1); SB0; LOADA(1, Ab0, Ab1); SB0;
      COMPUTE(0, Aa0, Aa1); FENCE8;
      STAGE(2, 0); SB0; LOADA(2, Aa0, Aa1); SB0;
      COMPUTE(1, Ab0, Ab1); FENCE8;
      STAGE(3, 1); SB0; LOADA(3, Ab0, Ab1); SB0;
      COMPUTE(0, Aa0, Aa1); FENCE8;
      STAGE(4, 0); SB0; LOADA(4, Aa0, Aa1); SB0;
      COMPUTE(1, Ab0, Ab1); FENCE8;
      STAGE(5, 1); SB0; LOADA(5, Ab0, Ab1); SB0;
      COMPUTE(0, Aa0, Aa1); FENCE8;
      STAGE(6, 0); SB0; LOADA(6, Aa0, Aa1); SB0;
      COMPUTE(1, Ab0, Ab1); FENCE8;
      STAGE(7, 1); SB0; LOADA(7, Ab0, Ab1); SB0;
      COMPUTE(0, Aa0, Aa1); FENCE8;
      COMPUTE(1, Ab0, Ab1);
#undef FENCE8
#undef COMPUTE
#undef LOADA
#undef STAGE
#undef SB0
    }

    // ---- LSTM epilogue: gates -> (creg, h) ----
#pragma unroll
    for (int r = 0; r < 16; ++r) {
      const int m = m0 + (r & 3) + 8 * (r >> 2) + 4 * lh;
      const int tv = tk[m];
      const float* Erow = E + (size_t)tv * G4;
      const float gi = acc[0][r] + Erow[u];
      const float gf = acc[1][r] + Erow[HID + u];
      const float gg = acc[2][r] + Erow[2 * HID + u];
      const float go = acc[3][r] + Erow[3 * HID + u];
      const float si = fsig(gi);
      const float sf = fsig(gf);
      const float so = fsig(go);
      const float nc = sf * creg[r] + si * ftanh(gg);
      creg[r] = nc;
      const float hv = so * ftanh(nc);
      h_out[(size_t)m * HID + u] = hv;
      ushort hi, lo;
      bf16split(hv, hi, lo);
      const size_t fo = ((size_t)(m >> 5) * 64 + (u >> 3)) * 256 + (size_t)(m & 31) * 8 + (u & 7);
      hout[fo] = hi;
      hout[HF + fo] = lo;
    }

    gridbar(bar, bar + 1);

    // ---- logits + softmax + sample (2 rows per wave) ----
    {
      const int o = l;
      float acc0 = 0.f, acc1 = 0.f;
      const float* h0p = h_out + (size_t)lb0 * HID;
      const float* h1p = h0p + HID;
#pragma unroll 4
      for (int k4 = 0; k4 < 128; ++k4) {
        const float4 wv = *(const float4*)(wlt + (size_t)(k4 * 64 + o) * 4);
        const float4 x0 = *(const float4*)(h0p + k4 * 4);
        const float4 x1 = *(const float4*)(h1p + k4 * 4);
        acc0 += wv.x * x0.x + wv.y * x0.y + wv.z * x0.z + wv.w * x0.w;
        acc1 += wv.x * x1.x + wv.y * x1.y + wv.z * x1.z + wv.w * x1.w;
      }
      const float bl = b_lin[o];
      uint32_t s0, s1;
      tf2x32(0u, 42u, 0u, (uint32_t)t, s0, s1);
      float lg[2] = {acc0 + bl, acc1 + bl};
#pragma unroll
      for (int r = 0; r < 2; ++r) {
        const int b = lb0 + r;
        const float logit = lg[r];
        float mx = logit;
#pragma unroll
        for (int d = 32; d; d >>= 1) mx = fmaxf(mx, __shfl_xor(mx, d));
        float e = expf(logit - mx);
        float ssum = e;
#pragma unroll
        for (int d = 32; d; d >>= 1) ssum += __shfl_xor(ssum, d);
        out[((size_t)b * STEPS + t) * NOUT + o] = e / ssum;

        uint32_t r0, r1;
        tf2x32(s0, s1, 0u, (uint32_t)(b * NOUT + o), r0, r1);
        const uint32_t bits = r0 ^ r1;
        float uu = __uint_as_float((bits >> 9) | 0x3f800000u) - 1.0f;
        uu = fmaxf(uu, 1.17549435e-38f);
        const float gmb = -logf(-logf(uu));
        float v = logit + gmb;
        int bi = o;
#pragma unroll
        for (int d = 32; d; d >>= 1) {
          float ov = __shfl_xor(v, d);
          int oi = __shfl_xor(bi, d);
          if (ov > v || (ov == v && oi < bi)) { v = ov; bi = oi; }
        }
        if (o == 0) tok[b] = bi;
      }
    }

    gridbar(bar, bar + 1);
  }
}

// ---------------- host ----------------
extern "C" void kernel_launch(void* const* d_in, const int* in_sizes, int n_in,
                              void* d_out, int out_size, void* d_ws, size_t ws_size,
                              hipStream_t stream) {
  const int*   x     = (const int*)d_in[0];
  const float* emb   = (const float*)d_in[1];
  const float* W_ih  = (const float*)d_in[2];
  const float* W_hh  = (const float*)d_in[3];
  const float* b_ih  = (const float*)d_in[4];
  const float* b_hh  = (const float*)d_in[5];
  const float* W_lin = (const float*)d_in[6];
  const float* b_lin = (const float*)d_in[7];
  float* out = (float*)d_out;

  float*  E    = (float*)d_ws;              // 131072 f32
  float*  h    = E + 131072;                // 2M f32
  float*  wlt  = h + HF;                    // 32768 f32
  ushort* hf0  = (ushort*)(wlt + 32768);    // 2 planes x 2M u16
  ushort* hf1  = hf0 + 2 * HF;
  ushort* wswz = hf1 + 2 * HF;              // 2M u16
  int*    tok  = (int*)(wswz + 2097152);
  unsigned* bar = (unsigned*)(tok + B_SZ);

  hipMemsetAsync(bar, 0, 2 * sizeof(unsigned), stream);

  eproj_kernel<<<64, 256, 0, stream>>>(emb, W_ih, b_ih, b_hh, E);
  wprep_whh<<<1024, 256, 0, stream>>>(W_hh, wswz);
  wprep_lin<<<128, 256, 0, stream>>>(W_lin, wlt);

  ctrl_persist<<<NBLK, 512, 0, stream>>>(x, wswz, E, wlt, b_lin,
                                         h, hf0, hf1, tok, out, bar);
}

// Round 8
// 2210.856 us; speedup vs baseline: 1.7571x; 1.7571x over previous
//
#include <hip/hip_runtime.h>
#include <stdint.h>
#include <math.h>

// Autoregressive LSTM controller. B=4096, EMB=128, HID=512, OUT=64, STEPS=20.
// Round 8: persistent kernel WITHOUT L2-nuking fences.
//  - Cross-block data (hf, h_out, tok) via sc0+sc1 ops (device-coherent at
//    L3/MALL, no cache invalidation). Read-only (W,E,wlt) stays L2-cached.
//  - c = block-private plain global fp32 (same block reads its own writes).
//  - Barrier: relaxed AGENT atomics + vmcnt(0) only.
//  - GEMM: manual counted-vmcnt pipeline (WAITA=12 / FENCE=8), rule-18
//    sched_barrier(0) after every asm waitcnt.
//  - Logits: block stages its 16 h rows -> LDS (one latency hit), LDS
//    broadcast reads for the dot products.

#define B_SZ  4096
#define EMB   128
#define HID   512
#define NOUT  64
#define STEPS 20
#define G4    2048
#define HF    ((size_t)B_SZ * HID)
#define NBLK  256

typedef __attribute__((ext_vector_type(8)))  short bf16x8;
typedef __attribute__((ext_vector_type(16))) float f32x16;
typedef __attribute__((ext_vector_type(4)))  uint  u32x4;
typedef __attribute__((ext_vector_type(4)))  float f32x4;

union AB { u32x4 q; bf16x8 v; };
union B8 { uint2 q[2]; bf16x8 v; };

// device-coherent (bypass L1+L2) memory ops
#define ALOAD16(D, P) asm volatile("global_load_dwordx4 %0, %1, off sc0 sc1" : "=v"(D) : "v"(P))
#define ALOAD4(D, P)  asm volatile("global_load_dword %0, %1, off sc0 sc1"   : "=v"(D) : "v"(P))
#define ASTORE4(P, V) asm volatile("global_store_dword %0, %1, off sc0 sc1" :: "v"(P), "v"(V) : "memory")
#define ASTORE2(P, V) asm volatile("global_store_short %0, %1, off sc0 sc1" :: "v"(P), "v"(V) : "memory")
#define SB0 __builtin_amdgcn_sched_barrier(0)

// ---------------- threefry2x32 (JAX partitionable semantics) ----------------
__device__ __forceinline__ void tf2x32(uint32_t k0, uint32_t k1,
                                       uint32_t x0, uint32_t x1,
                                       uint32_t& o0, uint32_t& o1) {
  const uint32_t ks2 = k0 ^ k1 ^ 0x1BD11BDAu;
#define TFR(r) { x0 += x1; x1 = (x1 << (r)) | (x1 >> (32 - (r))); x1 ^= x0; }
  x0 += k0; x1 += k1;
  TFR(13) TFR(15) TFR(26) TFR(6)
  x0 += k1;  x1 += ks2 + 1u;
  TFR(17) TFR(29) TFR(16) TFR(24)
  x0 += ks2; x1 += k0 + 2u;
  TFR(13) TFR(15) TFR(26) TFR(6)
  x0 += k0;  x1 += k1 + 3u;
  TFR(17) TFR(29) TFR(16) TFR(24)
  x0 += k1;  x1 += ks2 + 4u;
  TFR(13) TFR(15) TFR(26) TFR(6)
  x0 += ks2; x1 += k0 + 5u;
#undef TFR
  o0 = x0; o1 = x1;
}

// RNE split of fp32 into bf16 hi + bf16 lo
__device__ __forceinline__ void bf16split(float f, ushort& hi, ushort& lo) {
  uint32_t u = __float_as_uint(f);
  uint32_t r = u + 0x7fffu + ((u >> 16) & 1u);
  hi = (ushort)(r >> 16);
  float fh = __uint_as_float((r >> 16) << 16);
  float fl = f - fh;
  uint32_t v = __float_as_uint(fl);
  uint32_t r2 = v + 0x7fffu + ((v >> 16) & 1u);
  lo = (ushort)(r2 >> 16);
}

__device__ __forceinline__ void gload_lds16(const ushort* g, ushort* d) {
  __builtin_amdgcn_global_load_lds(
      (const __attribute__((address_space(1))) void*)g,
      (__attribute__((address_space(3))) void*)d, 16, 0, 0);
}

__device__ __forceinline__ float fsig(float x) {
  return __builtin_amdgcn_rcpf(1.f + __expf(-x));
}
__device__ __forceinline__ float ftanh(float x) {
  return 1.f - 2.f * __builtin_amdgcn_rcpf(1.f + __expf(2.f * x));
}

// grid barrier: relaxed atomics only, no cache maintenance
__device__ __forceinline__ void gridbar(unsigned* cnt, unsigned* gen) {
  asm volatile("s_waitcnt vmcnt(0)" ::: "memory");
  __syncthreads();
  if (threadIdx.x == 0) {
    unsigned g = __hip_atomic_load(gen, __ATOMIC_RELAXED, __HIP_MEMORY_SCOPE_AGENT);
    unsigned a = __hip_atomic_fetch_add(cnt, 1u, __ATOMIC_RELAXED, __HIP_MEMORY_SCOPE_AGENT);
    if (a == NBLK - 1) {
      __hip_atomic_store(cnt, 0u, __ATOMIC_RELAXED, __HIP_MEMORY_SCOPE_AGENT);
      __hip_atomic_fetch_add(gen, 1u, __ATOMIC_RELAXED, __HIP_MEMORY_SCOPE_AGENT);
    } else {
      while (__hip_atomic_load(gen, __ATOMIC_RELAXED, __HIP_MEMORY_SCOPE_AGENT) == g)
        __builtin_amdgcn_s_sleep(2);
    }
  }
  __syncthreads();
}

// ---------------- E_proj = emb @ W_ih.T + b_ih + b_hh (fp32, once) ----------
__global__ __launch_bounds__(256) void eproj_kernel(
    const float* __restrict__ emb, const float* __restrict__ W_ih,
    const float* __restrict__ b_ih, const float* __restrict__ b_hh,
    float* __restrict__ E) {
  const int t = blockIdx.x;
  __shared__ float es[EMB];
  for (int k = threadIdx.x; k < EMB; k += blockDim.x) es[k] = emb[t * EMB + k];
  __syncthreads();
  for (int j = threadIdx.x; j < G4; j += blockDim.x) {
    const float* w = W_ih + (size_t)j * EMB;
    float acc = 0.f;
#pragma unroll 8
    for (int k = 0; k < EMB; k += 4) {
      float4 wv = *(const float4*)(w + k);
      acc += wv.x * es[k] + wv.y * es[k + 1] + wv.z * es[k + 2] + wv.w * es[k + 3];
    }
    E[(size_t)t * G4 + j] = acc + b_ih[j] + b_hh[j];
  }
}

// ---------------- W_hh -> pre-swizzled staging mirror (once) ----------------
__global__ __launch_bounds__(256) void wprep_whh(
    const float* __restrict__ W_hh, ushort* __restrict__ wswz) {
  const int id = blockIdx.x * 256 + threadIdx.x;
  const int ub    = id >> 14;
  const int w14   = id & 16383;
  const int kt    = w14 >> 11;
  const int plane = (w14 >> 10) & 1;
  const int row   = (w14 >> 3) & 127;
  const int ec    = w14 & 7;
  const int grow = (row >> 5) * HID + ub * 32 + (row & 31);
  const int swz = (row & 15) << 2;
  ushort vals[8];
#pragma unroll
  for (int j = 0; j < 8; ++j) {
    const int e = ec * 8 + j;
    const int k = kt * 64 + (e ^ swz);
    ushort hi, lo;
    bf16split(W_hh[(size_t)grow * HID + k], hi, lo);
    vals[j] = plane ? lo : hi;
  }
  *(uint4*)(wswz + (size_t)id * 8) = *(const uint4*)vals;
}

// ---------------- W_lin -> coalesced transpose [k4][o][4] (once) ------------
__global__ __launch_bounds__(256) void wprep_lin(
    const float* __restrict__ W_lin, float* __restrict__ wlt) {
  const int id = blockIdx.x * 256 + threadIdx.x;
  const int j = id & 3, o = (id >> 2) & 63, k4 = id >> 8;
  wlt[id] = W_lin[(size_t)o * HID + k4 * 4 + j];
}

// ---------------- persistent controller: all 20 steps ----------------
__global__ __launch_bounds__(512, 2) void ctrl_persist(
    const int*    __restrict__ x,
    const ushort* __restrict__ wswz,
    const float*  __restrict__ E,
    const float*  __restrict__ wlt,
    const float*  __restrict__ b_lin,
    float*        __restrict__ c,      // block-private, plain cached
    float*        __restrict__ h_out,  // cross-block, sc1
    ushort*       __restrict__ hf0,    // cross-block, sc1
    ushort*       __restrict__ hf1,
    int*          __restrict__ tok,    // cross-block, sc1
    float*        __restrict__ out,
    unsigned*     __restrict__ bar)
{
  __shared__ ushort Bt[2][16384];      // 64 KB double buffer / logits h stage
  const int tid = threadIdx.x;
  const int w = tid >> 6, l = tid & 63;
  const int l31 = l & 31, lh = l >> 5;

  const int raw = blockIdx.x;
  const int xq = raw & 7, jq = raw >> 3;     // xq = XCD
  const int ub  = (xq & 3) * 4 + (jq & 3);
  const int mbi = (xq >> 2) * 8 + (jq >> 2);
  const int m0 = mbi * 256 + w * 32;
  const int u0 = ub * 32;
  const int u  = u0 + l31;
  const int o  = l;

  const ushort* wsrc = wswz + (size_t)ub * 131072 + (size_t)(w * 512 + l * 8);
  const int lb0 = raw * 16 + w * 2;

  f32x16 creg = {};                          // c resident in registers

  for (int t = 0; t < STEPS; ++t) {
    const ushort* hin  = (t & 1) ? hf1 : hf0;
    ushort*       hout = (t & 1) ? hf0 : hf1;

    // token preload for this wave's 32 rows (issued early, drained by fences)
    int mytok;
    if (t == 0) mytok = x[m0 + l31];
    else        ALOAD4(mytok, tok + m0 + l31);

    f32x16 acc[4] = {};

    if (t > 0) {
      const size_t abase = ((size_t)(m0 >> 5) * 64 + lh) * 256 + (size_t)l31 * 8;
      const ushort* a0 = hin + abase;
      const ushort* a1 = hin + HF + abase;
      AB Aa0[4], Aa1[4], Ab0[4], Ab1[4];

#define STAGE(KT, BUF) { _Pragma("unroll") for (int rr = 0; rr < 4; ++rr) \
    gload_lds16(wsrc + (size_t)(KT) * 16384 + rr * 4096, &Bt[BUF][w * 512 + rr * 4096]); }
#define LOADA(KT, A0v, A1v) { _Pragma("unroll") for (int kc = 0; kc < 4; ++kc) { \
    const size_t ko = (size_t)((KT) * 8 + kc * 2) * 256; \
    ALOAD16(A0v[kc].q, a0 + ko); ALOAD16(A1v[kc].q, a1 + ko); } }
#define COMPUTE(BUF, A0v, A1v) { __builtin_amdgcn_s_setprio(1); \
  _Pragma("unroll") for (int kc = 0; kc < 4; ++kc) { \
    _Pragma("unroll") for (int s = 0; s < 4; ++s) { \
      const int row = s * 32 + l31; \
      const int swz = (row & 15) << 2; \
      const int eb = kc * 16 + lh * 8; \
      const ushort* rb = &Bt[BUF][row * 64]; \
      B8 uh, ul; \
      uh.q[0] = *(const uint2*)(rb + ((eb)     ^ swz)); \
      uh.q[1] = *(const uint2*)(rb + ((eb + 4) ^ swz)); \
      ul.q[0] = *(const uint2*)(rb + 8192 + ((eb)     ^ swz)); \
      ul.q[1] = *(const uint2*)(rb + 8192 + ((eb + 4) ^ swz)); \
      acc[s] = __builtin_amdgcn_mfma_f32_32x32x16_bf16(A0v[kc].v, uh.v, acc[s], 0, 0, 0); \
      acc[s] = __builtin_amdgcn_mfma_f32_32x32x16_bf16(A1v[kc].v, uh.v, acc[s], 0, 0, 0); \
      acc[s] = __builtin_amdgcn_mfma_f32_32x32x16_bf16(A0v[kc].v, ul.v, acc[s], 0, 0, 0); } } \
  __builtin_amdgcn_s_setprio(0); }
#define WAITA  { asm volatile("s_waitcnt vmcnt(12)" ::: "memory"); SB0; }
#define WAITA0 { asm volatile("s_waitcnt vmcnt(0)"  ::: "memory"); SB0; }
#define FENCE  { asm volatile("s_waitcnt vmcnt(8)"  ::: "memory"); SB0; \
                 __builtin_amdgcn_s_barrier(); }

      STAGE(0, 0); SB0; LOADA(0, Aa0, Aa1); SB0;
      FENCE;   // drains tok + stage0, keeps A0 in flight
      STAGE(1, 1); SB0; LOADA(1, Ab0, Ab1); SB0; WAITA; COMPUTE(0, Aa0, Aa1); FENCE;
      STAGE(2, 0); SB0; LOADA(2, Aa0, Aa1); SB0; WAITA; COMPUTE(1, Ab0, Ab1); FENCE;
      STAGE(3, 1); SB0; LOADA(3, Ab0, Ab1); SB0; WAITA; COMPUTE(0, Aa0, Aa1); FENCE;
      STAGE(4, 0); SB0; LOADA(4, Aa0, Aa1); SB0; WAITA; COMPUTE(1, Ab0, Ab1); FENCE;
      STAGE(5, 1); SB0; LOADA(5, Ab0, Ab1); SB0; WAITA; COMPUTE(0, Aa0, Aa1); FENCE;
      STAGE(6, 0); SB0; LOADA(6, Aa0, Aa1); SB0; WAITA; COMPUTE(1, Ab0, Ab1); FENCE;
      STAGE(7, 1); SB0; LOADA(7, Ab0, Ab1); SB0; WAITA; COMPUTE(0, Aa0, Aa1); FENCE;
      WAITA0; COMPUTE(1, Ab0, Ab1);
#undef FENCE
#undef WAITA0
#undef WAITA
#undef COMPUTE
#undef LOADA
#undef STAGE
    }

    // ---- LSTM epilogue: gates -> (creg, h, hf) ----
#pragma unroll
    for (int r = 0; r < 16; ++r) {
      const int mi = (r & 3) + 8 * (r >> 2) + 4 * lh;
      const int m = m0 + mi;
      const int tk = __shfl(mytok, mi, 64);
      const float* Erow = E + (size_t)tk * G4;
      const float gi = acc[0][r] + Erow[u];
      const float gf = acc[1][r] + Erow[HID + u];
      const float gg = acc[2][r] + Erow[2 * HID + u];
      const float go = acc[3][r] + Erow[3 * HID + u];
      const float si = fsig(gi);
      const float sf = fsig(gf);
      const float so = fsig(go);
      const float nc = sf * creg[r] + si * ftanh(gg);
      creg[r] = nc;
      const float hv = so * ftanh(nc);
      ASTORE4(h_out + (size_t)m * HID + u, hv);
      ushort hi, lo;
      bf16split(hv, hi, lo);
      const size_t fo = ((size_t)(m >> 5) * 64 + (u >> 3)) * 256 + (size_t)(m & 31) * 8 + (u & 7);
      ASTORE2(hout + fo, hi);
      ASTORE2(hout + HF + fo, lo);
    }

    gridbar(bar, bar + 1);   // h/hf visible

    // ---- logits: stage block's 16 rows into LDS (one latency hit) ----
    {
      float* hlds = (float*)&Bt[0][0];
      const float* hsrc = h_out + (size_t)(raw * 16) * HID;
      u32x4 hr0, hr1, hr2, hr3;
      ALOAD16(hr0, hsrc + 0 * 2048 + tid * 4);
      ALOAD16(hr1, hsrc + 1 * 2048 + tid * 4);
      ALOAD16(hr2, hsrc + 2 * 2048 + tid * 4);
      ALOAD16(hr3, hsrc + 3 * 2048 + tid * 4);
      asm volatile("s_waitcnt vmcnt(0)" ::: "memory"); SB0;
      *(u32x4*)&hlds[0 * 2048 + tid * 4] = hr0;
      *(u32x4*)&hlds[1 * 2048 + tid * 4] = hr1;
      *(u32x4*)&hlds[2 * 2048 + tid * 4] = hr2;
      *(u32x4*)&hlds[3 * 2048 + tid * 4] = hr3;
      __syncthreads();

      const float* r0p = hlds + (size_t)(w * 2) * HID;
      const float* r1p = r0p + HID;
      float acc0 = 0.f, acc1 = 0.f;
#pragma unroll 8
      for (int k4 = 0; k4 < 128; ++k4) {
        const f32x4 wv = *(const f32x4*)(wlt + (size_t)(k4 * 64 + o) * 4);
        const f32x4 x0 = *(const f32x4*)(r0p + k4 * 4);
        const f32x4 x1 = *(const f32x4*)(r1p + k4 * 4);
        acc0 += wv[0] * x0[0] + wv[1] * x0[1] + wv[2] * x0[2] + wv[3] * x0[3];
        acc1 += wv[0] * x1[0] + wv[1] * x1[1] + wv[2] * x1[2] + wv[3] * x1[3];
      }
      const float bl = b_lin[o];
      uint32_t s0, s1;
      tf2x32(0u, 42u, 0u, (uint32_t)t, s0, s1);
      float lg[2] = {acc0 + bl, acc1 + bl};
#pragma unroll
      for (int r = 0; r < 2; ++r) {
        const int b = lb0 + r;
        const float logit = lg[r];
        float mx = logit;
#pragma unroll
        for (int d = 32; d; d >>= 1) mx = fmaxf(mx, __shfl_xor(mx, d));
        float e = expf(logit - mx);
        float ssum = e;
#pragma unroll
        for (int d = 32; d; d >>= 1) ssum += __shfl_xor(ssum, d);
        out[((size_t)b * STEPS + t) * NOUT + o] = e / ssum;

        uint32_t r0, r1;
        tf2x32(s0, s1, 0u, (uint32_t)(b * NOUT + o), r0, r1);
        const uint32_t bits = r0 ^ r1;
        float uu = __uint_as_float((bits >> 9) | 0x3f800000u) - 1.0f;
        uu = fmaxf(uu, 1.17549435e-38f);
        const float gmb = -logf(-logf(uu));
        float v = logit + gmb;
        int bi = o;
#pragma unroll
        for (int d = 32; d; d >>= 1) {
          float ov = __shfl_xor(v, d);
          int oi = __shfl_xor(bi, d);
          if (ov > v || (ov == v && oi < bi)) { v = ov; bi = oi; }
        }
        if (o == 0) ASTORE4(tok + b, bi);
      }
    }

    gridbar(bar, bar + 1);   // tok visible
  }
}

// ---------------- host ----------------
extern "C" void kernel_launch(void* const* d_in, const int* in_sizes, int n_in,
                              void* d_out, int out_size, void* d_ws, size_t ws_size,
                              hipStream_t stream) {
  const int*   x     = (const int*)d_in[0];
  const float* emb   = (const float*)d_in[1];
  const float* W_ih  = (const float*)d_in[2];
  const float* W_hh  = (const float*)d_in[3];
  const float* b_ih  = (const float*)d_in[4];
  const float* b_hh  = (const float*)d_in[5];
  const float* W_lin = (const float*)d_in[6];
  const float* b_lin = (const float*)d_in[7];
  float* out = (float*)d_out;

  float*  E    = (float*)d_ws;              // 131072 f32
  float*  c    = E + 131072;                // 2M f32 (block-private)
  float*  h    = c + HF;                    // 2M f32
  float*  wlt  = h + HF;                    // 32768 f32
  ushort* hf0  = (ushort*)(wlt + 32768);    // 2 planes x 2M u16
  ushort* hf1  = hf0 + 2 * HF;
  ushort* wswz = hf1 + 2 * HF;              // 2M u16
  int*    tok  = (int*)(wswz + 2097152);
  unsigned* bar = (unsigned*)(tok + B_SZ);

  hipMemsetAsync(bar, 0, 2 * sizeof(unsigned), stream);

  eproj_kernel<<<64, 256, 0, stream>>>(emb, W_ih, b_ih, b_hh, E);
  wprep_whh<<<1024, 256, 0, stream>>>(W_hh, wswz);
  wprep_lin<<<128, 256, 0, stream>>>(W_lin, wlt);

  ctrl_persist<<<NBLK, 512, 0, stream>>>(x, wswz, E, wlt, b_lin,
                                         c, h, hf0, hf1, tok, out, bar);
}

// Round 9
// 1811.897 us; speedup vs baseline: 2.1440x; 1.2202x over previous
//
#include <hip/hip_runtime.h>
#include <stdint.h>
#include <math.h>

// Autoregressive LSTM controller. B=4096, EMB=128, HID=512, OUT=64, STEPS=20.
// Round 9: persistent kernel with XCD-LOCAL decomposition.
//  - Each XCD owns 512 batch rows (2 mb-groups x 256): hf/h_out/tok are
//    produced and consumed on the SAME XCD -> sc0-only ops (L1 bypass,
//    L2-coherent) -- no L2 invalidation, no L3 round-trips.
//  - Per-XCD barriers (32 blocks, own cacheline), 2 per step.
//  - W/E read-only, plain cached; W streams L3->L2 (4 MB/XCD/step).
//  - GEMM: R6/R8 counted-vmcnt pipeline (WAITA=12/FENCE=8) + 8B-granule
//    zero-conflict LDS swizzle. c resident in registers for all 20 steps.
//  - RISK: relies on blockIdx%8 == XCD (m09-measured). Failure = visible
//    absmax blowup -> fallback is per-step launches.

#define B_SZ  4096
#define EMB   128
#define HID   512
#define NOUT  64
#define STEPS 20
#define G4    2048
#define HF    ((size_t)B_SZ * HID)
#define NBLK  256

typedef __attribute__((ext_vector_type(8)))  short bf16x8;
typedef __attribute__((ext_vector_type(16))) float f32x16;
typedef __attribute__((ext_vector_type(4)))  uint  u32x4;
typedef __attribute__((ext_vector_type(4)))  float f32x4;

union AB { u32x4 q; bf16x8 v; };
union B8 { uint2 q[2]; bf16x8 v; };

// L1-bypass (L2-coherent within XCD) memory ops
#define ALOAD16(D, P) asm volatile("global_load_dwordx4 %0, %1, off sc0" : "=v"(D) : "v"(P))
#define ALOAD4(D, P)  asm volatile("global_load_dword %0, %1, off sc0"   : "=v"(D) : "v"(P))
#define ASTORE4(P, V) asm volatile("global_store_dword %0, %1, off sc0" :: "v"(P), "v"(V) : "memory")
#define ASTORE2(P, V) asm volatile("global_store_short %0, %1, off sc0" :: "v"(P), "v"(V) : "memory")
#define SB0 __builtin_amdgcn_sched_barrier(0)

// ---------------- threefry2x32 (JAX partitionable semantics) ----------------
__device__ __forceinline__ void tf2x32(uint32_t k0, uint32_t k1,
                                       uint32_t x0, uint32_t x1,
                                       uint32_t& o0, uint32_t& o1) {
  const uint32_t ks2 = k0 ^ k1 ^ 0x1BD11BDAu;
#define TFR(r) { x0 += x1; x1 = (x1 << (r)) | (x1 >> (32 - (r))); x1 ^= x0; }
  x0 += k0; x1 += k1;
  TFR(13) TFR(15) TFR(26) TFR(6)
  x0 += k1;  x1 += ks2 + 1u;
  TFR(17) TFR(29) TFR(16) TFR(24)
  x0 += ks2; x1 += k0 + 2u;
  TFR(13) TFR(15) TFR(26) TFR(6)
  x0 += k0;  x1 += k1 + 3u;
  TFR(17) TFR(29) TFR(16) TFR(24)
  x0 += k1;  x1 += ks2 + 4u;
  TFR(13) TFR(15) TFR(26) TFR(6)
  x0 += ks2; x1 += k0 + 5u;
#undef TFR
  o0 = x0; o1 = x1;
}

// RNE split of fp32 into bf16 hi + bf16 lo
__device__ __forceinline__ void bf16split(float f, ushort& hi, ushort& lo) {
  uint32_t u = __float_as_uint(f);
  uint32_t r = u + 0x7fffu + ((u >> 16) & 1u);
  hi = (ushort)(r >> 16);
  float fh = __uint_as_float((r >> 16) << 16);
  float fl = f - fh;
  uint32_t v = __float_as_uint(fl);
  uint32_t r2 = v + 0x7fffu + ((v >> 16) & 1u);
  lo = (ushort)(r2 >> 16);
}

__device__ __forceinline__ void gload_lds16(const ushort* g, ushort* d) {
  __builtin_amdgcn_global_load_lds(
      (const __attribute__((address_space(1))) void*)g,
      (__attribute__((address_space(3))) void*)d, 16, 0, 0);
}

__device__ __forceinline__ float fsig(float x) {
  return __builtin_amdgcn_rcpf(1.f + __expf(-x));
}
__device__ __forceinline__ float ftanh(float x) {
  return 1.f - 2.f * __builtin_amdgcn_rcpf(1.f + __expf(2.f * x));
}

// per-XCD barrier: 32 blocks, relaxed atomics on this XCD's own cacheline
__device__ __forceinline__ void xcdbar(unsigned* cnt, unsigned* gen) {
  asm volatile("s_waitcnt vmcnt(0)" ::: "memory");
  __syncthreads();
  if (threadIdx.x == 0) {
    unsigned g = __hip_atomic_load(gen, __ATOMIC_RELAXED, __HIP_MEMORY_SCOPE_AGENT);
    unsigned a = __hip_atomic_fetch_add(cnt, 1u, __ATOMIC_RELAXED, __HIP_MEMORY_SCOPE_AGENT);
    if (a == 31) {
      __hip_atomic_store(cnt, 0u, __ATOMIC_RELAXED, __HIP_MEMORY_SCOPE_AGENT);
      __hip_atomic_fetch_add(gen, 1u, __ATOMIC_RELAXED, __HIP_MEMORY_SCOPE_AGENT);
    } else {
      while (__hip_atomic_load(gen, __ATOMIC_RELAXED, __HIP_MEMORY_SCOPE_AGENT) == g)
        __builtin_amdgcn_s_sleep(2);
    }
  }
  __syncthreads();
}

// ---------------- E_proj = emb @ W_ih.T + b_ih + b_hh (fp32, once) ----------
__global__ __launch_bounds__(256) void eproj_kernel(
    const float* __restrict__ emb, const float* __restrict__ W_ih,
    const float* __restrict__ b_ih, const float* __restrict__ b_hh,
    float* __restrict__ E) {
  const int t = blockIdx.x;
  __shared__ float es[EMB];
  for (int k = threadIdx.x; k < EMB; k += blockDim.x) es[k] = emb[t * EMB + k];
  __syncthreads();
  for (int j = threadIdx.x; j < G4; j += blockDim.x) {
    const float* w = W_ih + (size_t)j * EMB;
    float acc = 0.f;
#pragma unroll 8
    for (int k = 0; k < EMB; k += 4) {
      float4 wv = *(const float4*)(w + k);
      acc += wv.x * es[k] + wv.y * es[k + 1] + wv.z * es[k + 2] + wv.w * es[k + 3];
    }
    E[(size_t)t * G4 + j] = acc + b_ih[j] + b_hh[j];
  }
}

// ---------------- W_hh -> pre-swizzled staging mirror (once) ----------------
__global__ __launch_bounds__(256) void wprep_whh(
    const float* __restrict__ W_hh, ushort* __restrict__ wswz) {
  const int id = blockIdx.x * 256 + threadIdx.x;
  const int ub    = id >> 14;
  const int w14   = id & 16383;
  const int kt    = w14 >> 11;
  const int plane = (w14 >> 10) & 1;
  const int row   = (w14 >> 3) & 127;
  const int ec    = w14 & 7;
  const int grow = (row >> 5) * HID + ub * 32 + (row & 31);
  const int swz = (row & 15) << 2;
  ushort vals[8];
#pragma unroll
  for (int j = 0; j < 8; ++j) {
    const int e = ec * 8 + j;
    const int k = kt * 64 + (e ^ swz);
    ushort hi, lo;
    bf16split(W_hh[(size_t)grow * HID + k], hi, lo);
    vals[j] = plane ? lo : hi;
  }
  *(uint4*)(wswz + (size_t)id * 8) = *(const uint4*)vals;
}

// ---------------- W_lin -> coalesced transpose [k4][o][4] (once) ------------
__global__ __launch_bounds__(256) void wprep_lin(
    const float* __restrict__ W_lin, float* __restrict__ wlt) {
  const int id = blockIdx.x * 256 + threadIdx.x;
  const int j = id & 3, o = (id >> 2) & 63, k4 = id >> 8;
  wlt[id] = W_lin[(size_t)o * HID + k4 * 4 + j];
}

// ---------------- persistent controller: all 20 steps, XCD-local ------------
__global__ __launch_bounds__(512, 2) void ctrl_persist(
    const int*    __restrict__ x,
    const ushort* __restrict__ wswz,
    const float*  __restrict__ E,
    const float*  __restrict__ wlt,
    const float*  __restrict__ b_lin,
    float*        __restrict__ h_out,  // XCD-local shared, sc0
    ushort*       __restrict__ hf0,    // XCD-local shared, sc0
    ushort*       __restrict__ hf1,
    int*          __restrict__ tok,    // XCD-local shared, sc0
    float*        __restrict__ out,
    unsigned*     __restrict__ bar)
{
  __shared__ ushort Bt[2][16384];      // 64 KB double buffer / logits h stage
  const int tid = threadIdx.x;
  const int w = tid >> 6, l = tid & 63;
  const int l31 = l & 31, lh = l >> 5;

  // XCD-local ownership: xcd owns rows [xcd*512, xcd*512+512)
  const int raw = blockIdx.x;
  const int xcd  = raw & 7;
  const int slot = raw >> 3;           // 0..31
  const int ub   = slot & 15;
  const int mbi  = (xcd << 1) | (slot >> 4);
  const int m0 = mbi * 256 + w * 32;
  const int u0 = ub * 32;
  const int u  = u0 + l31;
  const int o  = l;

  const ushort* wsrc = wswz + (size_t)ub * 131072 + (size_t)(w * 512 + l * 8);
  const int lrow0 = mbi * 256 + (slot & 15) * 16;   // this block's logits rows
  const int lb0 = lrow0 + w * 2;                    // this wave's 2 rows
  unsigned* bcnt = bar + xcd * 32;
  unsigned* bgen = bcnt + 1;

  f32x16 creg = {};                          // c resident in registers

  for (int t = 0; t < STEPS; ++t) {
    const ushort* hin  = (t & 1) ? hf1 : hf0;
    ushort*       hout = (t & 1) ? hf0 : hf1;

    int mytok;
    if (t == 0) mytok = x[m0 + l31];
    else        ALOAD4(mytok, tok + m0 + l31);

    f32x16 acc[4] = {};

    if (t > 0) {
      const size_t abase = ((size_t)(m0 >> 5) * 64 + lh) * 256 + (size_t)l31 * 8;
      const ushort* a0 = hin + abase;
      const ushort* a1 = hin + HF + abase;
      AB Aa0[4], Aa1[4], Ab0[4], Ab1[4];

#define STAGE(KT, BUF) { _Pragma("unroll") for (int rr = 0; rr < 4; ++rr) \
    gload_lds16(wsrc + (size_t)(KT) * 16384 + rr * 4096, &Bt[BUF][w * 512 + rr * 4096]); }
#define LOADA(KT, A0v, A1v) { _Pragma("unroll") for (int kc = 0; kc < 4; ++kc) { \
    const size_t ko = (size_t)((KT) * 8 + kc * 2) * 256; \
    ALOAD16(A0v[kc].q, a0 + ko); ALOAD16(A1v[kc].q, a1 + ko); } }
#define COMPUTE(BUF, A0v, A1v) { __builtin_amdgcn_s_setprio(1); \
  _Pragma("unroll") for (int kc = 0; kc < 4; ++kc) { \
    _Pragma("unroll") for (int s = 0; s < 4; ++s) { \
      const int row = s * 32 + l31; \
      const int swz = (row & 15) << 2; \
      const int eb = kc * 16 + lh * 8; \
      const ushort* rb = &Bt[BUF][row * 64]; \
      B8 uh, ul; \
      uh.q[0] = *(const uint2*)(rb + ((eb)     ^ swz)); \
      uh.q[1] = *(const uint2*)(rb + ((eb + 4) ^ swz)); \
      ul.q[0] = *(const uint2*)(rb + 8192 + ((eb)     ^ swz)); \
      ul.q[1] = *(const uint2*)(rb + 8192 + ((eb + 4) ^ swz)); \
      acc[s] = __builtin_amdgcn_mfma_f32_32x32x16_bf16(A0v[kc].v, uh.v, acc[s], 0, 0, 0); \
      acc[s] = __builtin_amdgcn_mfma_f32_32x32x16_bf16(A1v[kc].v, uh.v, acc[s], 0, 0, 0); \
      acc[s] = __builtin_amdgcn_mfma_f32_32x32x16_bf16(A0v[kc].v, ul.v, acc[s], 0, 0, 0); } } \
  __builtin_amdgcn_s_setprio(0); }
#define WAITA  { asm volatile("s_waitcnt vmcnt(12)" ::: "memory"); SB0; }
#define WAITA0 { asm volatile("s_waitcnt vmcnt(0)"  ::: "memory"); SB0; }
#define FENCE  { asm volatile("s_waitcnt vmcnt(8)"  ::: "memory"); SB0; \
                 __builtin_amdgcn_s_barrier(); }

      STAGE(0, 0); SB0; LOADA(0, Aa0, Aa1); SB0;
      FENCE;   // drains tok + stage0, keeps A0 in flight
      STAGE(1, 1); SB0; LOADA(1, Ab0, Ab1); SB0; WAITA; COMPUTE(0, Aa0, Aa1); FENCE;
      STAGE(2, 0); SB0; LOADA(2, Aa0, Aa1); SB0; WAITA; COMPUTE(1, Ab0, Ab1); FENCE;
      STAGE(3, 1); SB0; LOADA(3, Ab0, Ab1); SB0; WAITA; COMPUTE(0, Aa0, Aa1); FENCE;
      STAGE(4, 0); SB0; LOADA(4, Aa0, Aa1); SB0; WAITA; COMPUTE(1, Ab0, Ab1); FENCE;
      STAGE(5, 1); SB0; LOADA(5, Ab0, Ab1); SB0; WAITA; COMPUTE(0, Aa0, Aa1); FENCE;
      STAGE(6, 0); SB0; LOADA(6, Aa0, Aa1); SB0; WAITA; COMPUTE(1, Ab0, Ab1); FENCE;
      STAGE(7, 1); SB0; LOADA(7, Ab0, Ab1); SB0; WAITA; COMPUTE(0, Aa0, Aa1); FENCE;
      WAITA0; COMPUTE(1, Ab0, Ab1);
#undef FENCE
#undef WAITA0
#undef WAITA
#undef COMPUTE
#undef LOADA
#undef STAGE
    }

    // ---- LSTM epilogue: gates -> (creg, h, hf) ----
#pragma unroll
    for (int r = 0; r < 16; ++r) {
      const int mi = (r & 3) + 8 * (r >> 2) + 4 * lh;
      const int m = m0 + mi;
      const int tk = __shfl(mytok, mi, 64);
      const float* Erow = E + (size_t)tk * G4;
      const float gi = acc[0][r] + Erow[u];
      const float gf = acc[1][r] + Erow[HID + u];
      const float gg = acc[2][r] + Erow[2 * HID + u];
      const float go = acc[3][r] + Erow[3 * HID + u];
      const float si = fsig(gi);
      const float sf = fsig(gf);
      const float so = fsig(go);
      const float nc = sf * creg[r] + si * ftanh(gg);
      creg[r] = nc;
      const float hv = so * ftanh(nc);
      ASTORE4(h_out + (size_t)m * HID + u, hv);
      ushort hi, lo;
      bf16split(hv, hi, lo);
      const size_t fo = ((size_t)(m >> 5) * 64 + (u >> 3)) * 256 + (size_t)(m & 31) * 8 + (u & 7);
      ASTORE2(hout + fo, hi);
      ASTORE2(hout + HF + fo, lo);
    }

    xcdbar(bcnt, bgen);   // h/hf visible (same-XCD L2)

    // ---- logits: stage block's 16 rows into LDS (one latency hit) ----
    {
      float* hlds = (float*)&Bt[0][0];
      const float* hsrc = h_out + (size_t)lrow0 * HID;
      u32x4 hr0, hr1, hr2, hr3;
      ALOAD16(hr0, hsrc + 0 * 2048 + tid * 4);
      ALOAD16(hr1, hsrc + 1 * 2048 + tid * 4);
      ALOAD16(hr2, hsrc + 2 * 2048 + tid * 4);
      ALOAD16(hr3, hsrc + 3 * 2048 + tid * 4);
      asm volatile("s_waitcnt vmcnt(0)" ::: "memory"); SB0;
      *(u32x4*)&hlds[0 * 2048 + tid * 4] = hr0;
      *(u32x4*)&hlds[1 * 2048 + tid * 4] = hr1;
      *(u32x4*)&hlds[2 * 2048 + tid * 4] = hr2;
      *(u32x4*)&hlds[3 * 2048 + tid * 4] = hr3;
      __syncthreads();

      const float* r0p = hlds + (size_t)(w * 2) * HID;
      const float* r1p = r0p + HID;
      float acc0 = 0.f, acc1 = 0.f;
#pragma unroll 8
      for (int k4 = 0; k4 < 128; ++k4) {
        const f32x4 wv = *(const f32x4*)(wlt + (size_t)(k4 * 64 + o) * 4);
        const f32x4 x0 = *(const f32x4*)(r0p + k4 * 4);
        const f32x4 x1 = *(const f32x4*)(r1p + k4 * 4);
        acc0 += wv[0] * x0[0] + wv[1] * x0[1] + wv[2] * x0[2] + wv[3] * x0[3];
        acc1 += wv[0] * x1[0] + wv[1] * x1[1] + wv[2] * x1[2] + wv[3] * x1[3];
      }
      const float bl = b_lin[o];
      uint32_t s0, s1;
      tf2x32(0u, 42u, 0u, (uint32_t)t, s0, s1);
      float lg[2] = {acc0 + bl, acc1 + bl};
#pragma unroll
      for (int r = 0; r < 2; ++r) {
        const int b = lb0 + r;
        const float logit = lg[r];
        float mx = logit;
#pragma unroll
        for (int d = 32; d; d >>= 1) mx = fmaxf(mx, __shfl_xor(mx, d));
        float e = expf(logit - mx);
        float ssum = e;
#pragma unroll
        for (int d = 32; d; d >>= 1) ssum += __shfl_xor(ssum, d);
        out[((size_t)b * STEPS + t) * NOUT + o] = e / ssum;

        uint32_t r0, r1;
        tf2x32(s0, s1, 0u, (uint32_t)(b * NOUT + o), r0, r1);
        const uint32_t bits = r0 ^ r1;
        float uu = __uint_as_float((bits >> 9) | 0x3f800000u) - 1.0f;
        uu = fmaxf(uu, 1.17549435e-38f);
        const float gmb = -logf(-logf(uu));
        float v = logit + gmb;
        int bi = o;
#pragma unroll
        for (int d = 32; d; d >>= 1) {
          float ov = __shfl_xor(v, d);
          int oi = __shfl_xor(bi, d);
          if (ov > v || (ov == v && oi < bi)) { v = ov; bi = oi; }
        }
        if (o == 0) ASTORE4(tok + b, bi);
      }
    }

    xcdbar(bcnt, bgen);   // tok visible (same-XCD L2)
  }
}

// ---------------- host ----------------
extern "C" void kernel_launch(void* const* d_in, const int* in_sizes, int n_in,
                              void* d_out, int out_size, void* d_ws, size_t ws_size,
                              hipStream_t stream) {
  const int*   x     = (const int*)d_in[0];
  const float* emb   = (const float*)d_in[1];
  const float* W_ih  = (const float*)d_in[2];
  const float* W_hh  = (const float*)d_in[3];
  const float* b_ih  = (const float*)d_in[4];
  const float* b_hh  = (const float*)d_in[5];
  const float* W_lin = (const float*)d_in[6];
  const float* b_lin = (const float*)d_in[7];
  float* out = (float*)d_out;

  float*  E    = (float*)d_ws;              // 131072 f32
  float*  h    = E + 131072;                // 2M f32
  float*  wlt  = h + HF;                    // 32768 f32
  ushort* hf0  = (ushort*)(wlt + 32768);    // 2 planes x 2M u16
  ushort* hf1  = hf0 + 2 * HF;
  ushort* wswz = hf1 + 2 * HF;              // 2M u16
  int*    tok  = (int*)(wswz + 2097152);
  unsigned* bar = (unsigned*)(tok + B_SZ);  // 8 XCD x 32 uints

  hipMemsetAsync(bar, 0, 8 * 32 * sizeof(unsigned), stream);

  eproj_kernel<<<64, 256, 0, stream>>>(emb, W_ih, b_ih, b_hh, E);
  wprep_whh<<<1024, 256, 0, stream>>>(W_hh, wswz);
  wprep_lin<<<128, 256, 0, stream>>>(W_lin, wlt);

  ctrl_persist<<<NBLK, 512, 0, stream>>>(x, wswz, E, wlt, b_lin,
                                         h, hf0, hf1, tok, out, bar);
}